// Round 5
// baseline (728.251 us; speedup 1.0000x reference)
//
#include <hip/hip_runtime.h>

#define B_ 64
#define H_ 96
#define N_ 16384
#define E_ 16
#define CHUNK_B 16        // batches per chunk: 16*96*16384*4B = 100 MB < 256 MB L3

// ---------------------------------------------------------------------------
// Kernel 1: per-(b,h) row sum for one batch-chunk. One 256-thread block per
// row; each row is 16384 contiguous floats (64 KB) -> float4, 16 iters/thread.
// grid = CHUNK_B * H_ = 1536 blocks; x/sums pre-offset to chunk start.
// ---------------------------------------------------------------------------
__global__ __launch_bounds__(256) void row_reduce(const float4* __restrict__ x,
                                                  float* __restrict__ sums) {
    const int row = blockIdx.x;
    const float4* p = x + (size_t)row * (N_ / 4);
    float acc = 0.f;
#pragma unroll 4
    for (int i = threadIdx.x; i < N_ / 4; i += 256) {
        float4 v = p[i];
        acc += (v.x + v.y) + (v.z + v.w);
    }
#pragma unroll
    for (int off = 32; off > 0; off >>= 1) acc += __shfl_down(acc, off, 64);
    __shared__ float wsum[4];
    if ((threadIdx.x & 63) == 0) wsum[threadIdx.x >> 6] = acc;
    __syncthreads();
    if (threadIdx.x == 0) sums[row] = (wsum[0] + wsum[1]) + (wsum[2] + wsum[3]);
}

// ---------------------------------------------------------------------------
// Kernel 2: per-batch gate for one chunk: scores = (sums/N) @ gate_w + gate_b,
// argmax (first-max, matching jnp.argmax tie-break), gather gamma/beta.
// grid = CHUNK_B blocks x 1 wave; sums/gb/bb pre-offset to chunk start.
// ---------------------------------------------------------------------------
__global__ __launch_bounds__(64) void gate_kernel(const float* __restrict__ sums,
                                                  const float* __restrict__ gate_w,
                                                  const float* __restrict__ gate_b,
                                                  const float* __restrict__ gammas,
                                                  const float* __restrict__ betas,
                                                  float* __restrict__ gb,
                                                  float* __restrict__ bb) {
    const int b = blockIdx.x;
    __shared__ float gi[H_];
    __shared__ float sc[E_];
    for (int h = threadIdx.x; h < H_; h += 64)
        gi[h] = sums[b * H_ + h] * (1.0f / N_);
    __syncthreads();
    const int e = threadIdx.x;
    if (e < E_) {
        float s = gate_b[e];
#pragma unroll
        for (int h = 0; h < H_; ++h) s = fmaf(gi[h], gate_w[h * E_ + e], s);
        sc[e] = s;
    }
    __syncthreads();
    if (threadIdx.x == 0) {
        int best = 0;
        float bs = sc[0];
#pragma unroll
        for (int e2 = 1; e2 < E_; ++e2) {
            if (sc[e2] > bs) { bs = sc[e2]; best = e2; }
        }
        gb[b] = gammas[best];
        bb[b] = betas[best];
    }
}

// ---------------------------------------------------------------------------
// Kernel 3: out = x * g[b] + beta[b] for one chunk. 2D grid (64, CHUNK_B) =
// 1024 blocks -> 4 blocks/CU, 16 waves/CU (hide HBM latency).
// b = blockIdx.y -> wave-uniform scalars, no int-div in the loop.
// x/out/gb/bb pre-offset to chunk start. Reads should hit L3 (chunk was just
// streamed by row_reduce).
// ---------------------------------------------------------------------------
__global__ __launch_bounds__(256) void apply_affine(const float4* __restrict__ x,
                                                    const float* __restrict__ gb,
                                                    const float* __restrict__ bb,
                                                    float4* __restrict__ out) {
    const int hn4 = H_ * N_ / 4;                  // 393216 float4 per batch
    const int b = blockIdx.y;
    const float g  = gb[b];
    const float be = bb[b];
    const size_t base = (size_t)b * hn4;
    const int stride = gridDim.x * blockDim.x;    // 64*256 = 16384
#pragma unroll 4
    for (int i = blockIdx.x * blockDim.x + threadIdx.x; i < hn4; i += stride) {
        float4 v = x[base + i];
        v.x = fmaf(v.x, g, be);
        v.y = fmaf(v.y, g, be);
        v.z = fmaf(v.z, g, be);
        v.w = fmaf(v.w, g, be);
        out[base + i] = v;
    }
}

extern "C" void kernel_launch(void* const* d_in, const int* in_sizes, int n_in,
                              void* d_out, int out_size, void* d_ws, size_t ws_size,
                              hipStream_t stream) {
    const float* x      = (const float*)d_in[0];   // [B,H,N,1]
    const float* gammas = (const float*)d_in[1];   // [E]
    const float* betas  = (const float*)d_in[2];   // [E]
    const float* gate_w = (const float*)d_in[3];   // [H,E]
    const float* gate_b = (const float*)d_in[4];   // [E]
    float* out = (float*)d_out;

    // workspace layout: sums[B*H] | gb[B] | bb[B]
    float* sums = (float*)d_ws;
    float* gb   = sums + B_ * H_;
    float* bb   = gb + B_;

    const size_t batch_elems4 = (size_t)H_ * N_ / 4;   // float4 per batch

    for (int b0 = 0; b0 < B_; b0 += CHUNK_B) {
        const float4* xc  = (const float4*)x + (size_t)b0 * batch_elems4;
        float4*       oc  = (float4*)out     + (size_t)b0 * batch_elems4;
        float*        sc_ = sums + b0 * H_;

        row_reduce<<<CHUNK_B * H_, 256, 0, stream>>>(xc, sc_);
        gate_kernel<<<CHUNK_B, 64, 0, stream>>>(sc_, gate_w, gate_b, gammas, betas,
                                                gb + b0, bb + b0);
        apply_affine<<<dim3(64, CHUNK_B), 256, 0, stream>>>(xc, gb + b0, bb + b0, oc);
    }
}

// Round 7
// 727.586 us; speedup vs baseline: 1.0009x; 1.0009x over previous
//
#include <hip/hip_runtime.h>

#define B_ 64
#define H_ 96
#define N_ 16384
#define E_ 16

// ---------------------------------------------------------------------------
// A/B EXPERIMENT (R6/R7): monolithic 3-dispatch (no batch chunking) vs R5's
// 4-chunk schedule (728 us). Decomposes dur_us into harness-constant vs ours.
// ---------------------------------------------------------------------------

// Kernel 1: per-(b,h) row sum. One 256-thread block per row (64 KB row),
// float4 loads, 16 iters/thread. 6144 blocks.
__global__ __launch_bounds__(256) void row_reduce(const float4* __restrict__ x,
                                                  float* __restrict__ sums) {
    const int row = blockIdx.x;
    const float4* p = x + (size_t)row * (N_ / 4);
    float acc = 0.f;
#pragma unroll 4
    for (int i = threadIdx.x; i < N_ / 4; i += 256) {
        float4 v = p[i];
        acc += (v.x + v.y) + (v.z + v.w);
    }
#pragma unroll
    for (int off = 32; off > 0; off >>= 1) acc += __shfl_down(acc, off, 64);
    __shared__ float wsum[4];
    if ((threadIdx.x & 63) == 0) wsum[threadIdx.x >> 6] = acc;
    __syncthreads();
    if (threadIdx.x == 0) sums[row] = (wsum[0] + wsum[1]) + (wsum[2] + wsum[3]);
}

// Kernel 2: per-batch gate: scores = (sums/N) @ gate_w + gate_b, first-max
// argmax (jnp.argmax tie-break), gather gamma/beta. 64 blocks x 1 wave.
__global__ __launch_bounds__(64) void gate_kernel(const float* __restrict__ sums,
                                                  const float* __restrict__ gate_w,
                                                  const float* __restrict__ gate_b,
                                                  const float* __restrict__ gammas,
                                                  const float* __restrict__ betas,
                                                  float* __restrict__ gb,
                                                  float* __restrict__ bb) {
    const int b = blockIdx.x;
    __shared__ float gi[H_];
    __shared__ float sc[E_];
    for (int h = threadIdx.x; h < H_; h += 64)
        gi[h] = sums[b * H_ + h] * (1.0f / N_);
    __syncthreads();
    const int e = threadIdx.x;
    if (e < E_) {
        float s = gate_b[e];
#pragma unroll
        for (int h = 0; h < H_; ++h) s = fmaf(gi[h], gate_w[h * E_ + e], s);
        sc[e] = s;
    }
    __syncthreads();
    if (threadIdx.x == 0) {
        int best = 0;
        float bs = sc[0];
#pragma unroll
        for (int e2 = 1; e2 < E_; ++e2) {
            if (sc[e2] > bs) { bs = sc[e2]; best = e2; }
        }
        gb[b] = gammas[best];
        bb[b] = betas[best];
    }
}

// Kernel 3: out = x * g[b] + beta[b]. 2D grid (64, B_) = 4096 blocks,
// b = blockIdx.y -> wave-uniform scalars, no int-div. 24 float4/thread.
__global__ __launch_bounds__(256) void apply_affine(const float4* __restrict__ x,
                                                    const float* __restrict__ gb,
                                                    const float* __restrict__ bb,
                                                    float4* __restrict__ out) {
    const int hn4 = H_ * N_ / 4;                  // 393216 float4 per batch
    const int b = blockIdx.y;
    const float g  = gb[b];
    const float be = bb[b];
    const size_t base = (size_t)b * hn4;
    const int stride = gridDim.x * blockDim.x;    // 64*256 = 16384
#pragma unroll 4
    for (int i = blockIdx.x * blockDim.x + threadIdx.x; i < hn4; i += stride) {
        float4 v = x[base + i];
        v.x = fmaf(v.x, g, be);
        v.y = fmaf(v.y, g, be);
        v.z = fmaf(v.z, g, be);
        v.w = fmaf(v.w, g, be);
        out[base + i] = v;
    }
}

extern "C" void kernel_launch(void* const* d_in, const int* in_sizes, int n_in,
                              void* d_out, int out_size, void* d_ws, size_t ws_size,
                              hipStream_t stream) {
    const float* x      = (const float*)d_in[0];   // [B,H,N,1]
    const float* gammas = (const float*)d_in[1];   // [E]
    const float* betas  = (const float*)d_in[2];   // [E]
    const float* gate_w = (const float*)d_in[3];   // [H,E]
    const float* gate_b = (const float*)d_in[4];   // [E]
    float* out = (float*)d_out;

    // workspace layout: sums[B*H] | gb[B] | bb[B]
    float* sums = (float*)d_ws;
    float* gb   = sums + B_ * H_;
    float* bb   = gb + B_;

    row_reduce<<<B_ * H_, 256, 0, stream>>>((const float4*)x, sums);
    gate_kernel<<<B_, 64, 0, stream>>>(sums, gate_w, gate_b, gammas, betas, gb, bb);
    apply_affine<<<dim3(64, B_), 256, 0, stream>>>((const float4*)x, gb, bb, (float4*)out);
}

// Round 8
// 698.545 us; speedup vs baseline: 1.0425x; 1.0416x over previous
//
#include <hip/hip_runtime.h>

#define B_ 64
#define H_ 96
#define N_ 16384
#define E_ 16

typedef float f32x4 __attribute__((ext_vector_type(4)));

// ---------------------------------------------------------------------------
// R8: monolithic 3-dispatch + NONTEMPORAL loads/stores on all big streams.
// All x/out traffic is touch-once (L3 chunk A/B showed re-read residency is
// worthless: 728.25 vs 727.59 us) -> mark streams evict-first to cut cache
// churn. Everything else identical to R7 baseline (727.6 us).
// ---------------------------------------------------------------------------

// Kernel 1: per-(b,h) row sum. One 256-thread block per row (64 KB row),
// nontemporal float4 loads, 16 iters/thread. 6144 blocks.
__global__ __launch_bounds__(256) void row_reduce(const f32x4* __restrict__ x,
                                                  float* __restrict__ sums) {
    const int row = blockIdx.x;
    const f32x4* p = x + (size_t)row * (N_ / 4);
    float acc = 0.f;
#pragma unroll 4
    for (int i = threadIdx.x; i < N_ / 4; i += 256) {
        f32x4 v = __builtin_nontemporal_load(&p[i]);
        acc += (v.x + v.y) + (v.z + v.w);
    }
#pragma unroll
    for (int off = 32; off > 0; off >>= 1) acc += __shfl_down(acc, off, 64);
    __shared__ float wsum[4];
    if ((threadIdx.x & 63) == 0) wsum[threadIdx.x >> 6] = acc;
    __syncthreads();
    if (threadIdx.x == 0) sums[row] = (wsum[0] + wsum[1]) + (wsum[2] + wsum[3]);
}

// Kernel 2: per-batch gate: scores = (sums/N) @ gate_w + gate_b, first-max
// argmax (jnp.argmax tie-break), gather gamma/beta. 64 blocks x 1 wave.
__global__ __launch_bounds__(64) void gate_kernel(const float* __restrict__ sums,
                                                  const float* __restrict__ gate_w,
                                                  const float* __restrict__ gate_b,
                                                  const float* __restrict__ gammas,
                                                  const float* __restrict__ betas,
                                                  float* __restrict__ gb,
                                                  float* __restrict__ bb) {
    const int b = blockIdx.x;
    __shared__ float gi[H_];
    __shared__ float sc[E_];
    for (int h = threadIdx.x; h < H_; h += 64)
        gi[h] = sums[b * H_ + h] * (1.0f / N_);
    __syncthreads();
    const int e = threadIdx.x;
    if (e < E_) {
        float s = gate_b[e];
#pragma unroll
        for (int h = 0; h < H_; ++h) s = fmaf(gi[h], gate_w[h * E_ + e], s);
        sc[e] = s;
    }
    __syncthreads();
    if (threadIdx.x == 0) {
        int best = 0;
        float bs = sc[0];
#pragma unroll
        for (int e2 = 1; e2 < E_; ++e2) {
            if (sc[e2] > bs) { bs = sc[e2]; best = e2; }
        }
        gb[b] = gammas[best];
        bb[b] = betas[best];
    }
}

// Kernel 3: out = x * g[b] + beta[b]. 2D grid (64, B_) = 4096 blocks,
// b = blockIdx.y -> wave-uniform scalars. Nontemporal load+store: both
// streams are touch-once.
__global__ __launch_bounds__(256) void apply_affine(const f32x4* __restrict__ x,
                                                    const float* __restrict__ gb,
                                                    const float* __restrict__ bb,
                                                    f32x4* __restrict__ out) {
    const int hn4 = H_ * N_ / 4;                  // 393216 float4 per batch
    const int b = blockIdx.y;
    const float g  = gb[b];
    const float be = bb[b];
    const size_t base = (size_t)b * hn4;
    const int stride = gridDim.x * blockDim.x;    // 64*256 = 16384
#pragma unroll 4
    for (int i = blockIdx.x * blockDim.x + threadIdx.x; i < hn4; i += stride) {
        f32x4 v = __builtin_nontemporal_load(&x[base + i]);
        f32x4 r;
        r.x = fmaf(v.x, g, be);
        r.y = fmaf(v.y, g, be);
        r.z = fmaf(v.z, g, be);
        r.w = fmaf(v.w, g, be);
        __builtin_nontemporal_store(r, &out[base + i]);
    }
}

extern "C" void kernel_launch(void* const* d_in, const int* in_sizes, int n_in,
                              void* d_out, int out_size, void* d_ws, size_t ws_size,
                              hipStream_t stream) {
    const float* x      = (const float*)d_in[0];   // [B,H,N,1]
    const float* gammas = (const float*)d_in[1];   // [E]
    const float* betas  = (const float*)d_in[2];   // [E]
    const float* gate_w = (const float*)d_in[3];   // [H,E]
    const float* gate_b = (const float*)d_in[4];   // [E]
    float* out = (float*)d_out;

    // workspace layout: sums[B*H] | gb[B] | bb[B]
    float* sums = (float*)d_ws;
    float* gb   = sums + B_ * H_;
    float* bb   = gb + B_;

    row_reduce<<<B_ * H_, 256, 0, stream>>>((const f32x4*)x, sums);
    gate_kernel<<<B_, 64, 0, stream>>>(sums, gate_w, gate_b, gammas, betas, gb, bb);
    apply_affine<<<dim3(64, B_), 256, 0, stream>>>((const f32x4*)x, gb, bb, (f32x4*)out);
}